// Round 8
// baseline (1150.706 us; speedup 1.0000x reference)
//
#include <hip/hip_runtime.h>
#include <hip/hip_cooperative_groups.h>

namespace cg = cooperative_groups;

// Problem constants (fixed by the reference's setup_inputs)
#define BATCH   256
#define N_PER   4096
#define EMBED   16
#define HID     32
#define NOTE    64
#define LSTM_D  64
#define T_LEN   128
#define VOCAB   200
#define HSTR    (BATCH * HID)     // floats per slot (tree-inner layout)
#define GRID    512
#define NGRP    ((GRID * 256) / 32)

// meta header (ints)
#define MH_C0    0     // kind-0 leaf count (per tree)
#define MH_C1    1     // kind-1 ptr count
#define MH_CNT   2     // [2..6] internal count at level 1..5
#define MH_P     7     // total parents (levels 1..5 + root); root pidx = P-1
#define MH_PBASE 8     // [8..12] pidx base of level 1..5
// meta arrays (ints)
#define OFF_K0N   64
#define OFF_K1N   (OFF_K0N + N_PER)
#define OFF_PLIST (OFF_K1N + N_PER)
#define OFF_N2S   (OFF_PLIST + N_PER)    // node -> h slot (CSR position)
#define OFF_COFF  (OFF_N2S + N_PER)      // N_PER+1 entries, pidx-indexed
// ws byte offsets
#define N2P_BYTE     (128 * 1024)            // [N_PER] ints (build scratch)
#define DEG_BYTE     (160 * 1024)            // [N_PER] ints (build scratch)
#define EAW_BYTE     (1024 * 1024)           // [VOCAB][HID]
#define EBW_BYTE     (EAW_BYTE + 32 * 1024)
#define FNPRE_BYTE   (1536 * 1024)           // [BATCH][HID]
#define PTRPRE_BYTE  (2ull * 1024 * 1024)    // [BATCH][T_LEN][HID] = 4 MB
#define ROOTPART_BYTE (6656ull * 1024)       // [16][BATCH][HID] = 512 KB
#define H_BYTE       (8ull * 1024 * 1024)    // [slot][BATCH][HID]

struct KParams {
    const int *kind, *height, *parent, *tok_a, *tok_b, *ptr_time;
    const float *first_notes, *lstm_out, *embedding;
    const float *leaf_w1, *leaf_b1, *leaf_w2, *leaf_b2;
    const float *node_w, *node_b, *ptr_w, *ptr_b;
    const float *ff_w1, *ff_b1, *ff_w2, *ff_b2, *tail_w, *tail_b;
    int *meta, *n2p, *deg;
    float *eaw, *ebw, *fn_pre, *ptr_pre, *rootpart, *h, *out;
};

// ---------------------------------------------------------------------------
// Structure build, 256 threads, 16 nodes/thread. n2p/deg scratch in GLOBAL
// memory (single block) so the shared-LDS footprint stays ~3 KB.
// ---------------------------------------------------------------------------
__device__ __forceinline__ void phase_build(const KParams& p)
{
    __shared__ unsigned long long sp64[256];
    __shared__ int spint[256];
    __shared__ int sbases[8], stot[8];

    int* n2p  = p.n2p;
    int* deg  = p.deg;
    int* meta = p.meta;
    const int t  = threadIdx.x;
    const int i0 = t * 16;

    int myb[16];
    unsigned long long clo = 0, chi = 0;
    #pragma unroll
    for (int q = 0; q < 16; ++q) {
        int i = i0 + q;
        int hgt = p.height[i];
        int b;
        if (hgt > 0) { b = 1 + hgt; if (b > 7) b = 7; }  // lvl1..5 -> 2..6, root -> 7
        else b = (p.kind[i] == 0) ? 0 : 1;
        myb[q] = b;
        if (b < 4) clo += 1ull << (16 * b);
        else       chi += 1ull << (16 * (b - 4));
    }
    sp64[t] = clo; __syncthreads();
    for (int off = 1; off < 256; off <<= 1) {
        unsigned long long v = (t >= off) ? sp64[t - off] : 0ull; __syncthreads();
        sp64[t] += v; __syncthreads();
    }
    unsigned long long ilo = sp64[t];
    if (t == 255) {
        stot[0] = (int)(ilo & 0xFFFF);         stot[1] = (int)((ilo >> 16) & 0xFFFF);
        stot[2] = (int)((ilo >> 32) & 0xFFFF); stot[3] = (int)((ilo >> 48) & 0xFFFF);
    }
    __syncthreads();
    sp64[t] = chi; __syncthreads();
    for (int off = 1; off < 256; off <<= 1) {
        unsigned long long v = (t >= off) ? sp64[t - off] : 0ull; __syncthreads();
        sp64[t] += v; __syncthreads();
    }
    unsigned long long ihi = sp64[t];
    if (t == 255) {
        stot[4] = (int)(ihi & 0xFFFF);         stot[5] = (int)((ihi >> 16) & 0xFFFF);
        stot[6] = (int)((ihi >> 32) & 0xFFFF); stot[7] = (int)((ihi >> 48) & 0xFFFF);
    }
    __syncthreads();
    if (t == 0) {
        int s = 0;
        for (int b = 0; b < 8; ++b) { sbases[b] = s; s += stot[b]; }
        meta[MH_C0] = stot[0];
        meta[MH_C1] = stot[1];
        for (int l = 0; l < 5; ++l) meta[MH_CNT + l]   = stot[2 + l];
        for (int l = 0; l < 5; ++l) meta[MH_PBASE + l] = sbases[2 + l] - sbases[2];
        meta[MH_P] = (sbases[7] - sbases[2]) + stot[7];
    }
    __syncthreads();
    unsigned long long exlo = ilo - clo, exhi = ihi - chi;
    #pragma unroll
    for (int q = 0; q < 16; ++q) {
        int i = i0 + q, b = myb[q];
        int pos;
        if (b < 4) { pos = (int)((exlo >> (16 * b)) & 0xFFFF); exlo += 1ull << (16 * b); }
        else       { pos = (int)((exhi >> (16 * (b - 4))) & 0xFFFF); exhi += 1ull << (16 * (b - 4)); }
        if (b == 0)      meta[OFF_K0N + pos] = i;
        else if (b == 1) meta[OFF_K1N + pos] = i;
        else {
            int pidx = (sbases[b] - sbases[2]) + pos;
            meta[OFF_PLIST + pidx] = i;
            n2p[i] = pidx;
        }
    }
    #pragma unroll
    for (int q = 0; q < 16; ++q) deg[i0 + q] = 0;
    __syncthreads();
    #pragma unroll
    for (int q = 0; q < 16; ++q) {
        int i = i0 + q;
        if (i != 0) atomicAdd(&deg[n2p[p.parent[i]]], 1);
    }
    __syncthreads();
    int dv[16]; int csum16 = 0;
    #pragma unroll
    for (int q = 0; q < 16; ++q) { dv[q] = deg[i0 + q]; csum16 += dv[q]; }
    spint[t] = csum16; __syncthreads();
    for (int off = 1; off < 256; off <<= 1) {
        int v = (t >= off) ? spint[t - off] : 0; __syncthreads();
        spint[t] += v; __syncthreads();
    }
    int ex = spint[t] - csum16;
    #pragma unroll
    for (int q = 0; q < 16; ++q) {
        meta[OFF_COFF + i0 + q] = ex;
        deg[i0 + q] = ex;          // cursor
        ex += dv[q];
    }
    if (t == 255) meta[OFF_COFF + N_PER] = ex;
    __syncthreads();
    #pragma unroll
    for (int q = 0; q < 16; ++q) {
        int i = i0 + q;
        if (i != 0) {
            int slot = atomicAdd(&deg[n2p[p.parent[i]]], 1);
            meta[OFF_N2S + i] = slot;
        }
    }
}

// ---------------------------------------------------------------------------
// Prep: eaw/ebw tables, fn_pre, ptr_pre GEMV. wt/nw = participating threads.
// ---------------------------------------------------------------------------
__device__ __forceinline__ void phase_prep(const KParams& p, int wt, int nw, int lane)
{
    for (int idx = wt; idx < VOCAB * HID; idx += nw) {
        int v = idx >> 5, d = idx & 31;
        float sa = 0.f, sb = 0.f;
        #pragma unroll
        for (int k = 0; k < EMBED; ++k) {
            float e = p.embedding[v * EMBED + k];
            sa += e * p.node_w[k * HID + d];
            sb += e * p.node_w[(EMBED + k) * HID + d];
        }
        p.eaw[idx] = sa;
        p.ebw[idx] = sb;
    }
    int wg = wt >> 5, nwg = nw >> 5;
    for (int r = wg; r < BATCH; r += nwg) {
        const float* fn = p.first_notes + (size_t)r * NOTE;
        float v = p.ptr_b[lane];
        #pragma unroll
        for (int k = 0; k < NOTE; ++k) v += fn[k] * p.ptr_w[k * HID + lane];
        p.fn_pre[r * HID + lane] = v;
    }
    for (int r = wg; r < BATCH * T_LEN; r += nwg) {
        const float* lo = p.lstm_out + (size_t)r * LSTM_D;
        float v = 0.f;
        #pragma unroll
        for (int k = 0; k < LSTM_D; ++k) v += lo[k] * p.ptr_w[(NOTE + k) * HID + lane];
        p.ptr_pre[r * HID + lane] = v;
    }
}

// ---------------------------------------------------------------------------
// Leaves + ptr rows -> h (tree-inner coalesced writes)
// ---------------------------------------------------------------------------
__device__ __forceinline__ void phase_leafptr(const KParams& p, int ggrp, int ngrp, int lane)
{
    const int* meta = p.meta;
    const int* N2S  = meta + OFF_N2S;
    int c0 = meta[MH_C0];
    const int* K0N = meta + OFF_K0N;
    float w1a[EMBED], w1b[EMBED], w2c[HID];
    #pragma unroll
    for (int k = 0; k < EMBED; ++k) {
        w1a[k] = p.leaf_w1[k * HID + lane];
        w1b[k] = p.leaf_w1[(EMBED + k) * HID + lane];
    }
    #pragma unroll
    for (int k = 0; k < HID; ++k) w2c[k] = p.leaf_w2[k * HID + lane];
    float b1 = p.leaf_b1[lane], b2 = p.leaf_b2[lane];

    int tot = c0 * BATCH;
    for (int i = ggrp; i < tot; i += ngrp) {
        int j = i >> 8, tree = i & 255;
        int node = K0N[j], slot = N2S[node];
        int gn = tree * N_PER + node;
        const float* ea = p.embedding + p.tok_a[gn] * EMBED;
        const float* eb = p.embedding + p.tok_b[gn] * EMBED;
        float hid = b1;
        #pragma unroll
        for (int k = 0; k < EMBED; ++k) hid += ea[k] * w1a[k];
        #pragma unroll
        for (int k = 0; k < EMBED; ++k) hid += eb[k] * w1b[k];
        float v = b2;
        #pragma unroll
        for (int k = 0; k < HID; ++k) v += __shfl(hid, k, 32) * w2c[k];
        p.h[(size_t)slot * HSTR + tree * HID + lane] = v;
    }

    int c1 = meta[MH_C1];
    const int* K1N = meta + OFF_K1N;
    int tot1 = c1 * BATCH;
    for (int i = ggrp; i < tot1; i += ngrp) {
        int j = i >> 8, tree = i & 255;
        int node = K1N[j], slot = N2S[node];
        int tt = p.ptr_time[tree * N_PER + node];
        float v = p.fn_pre[tree * HID + lane]
                + p.ptr_pre[((size_t)tree * T_LEN + tt) * HID + lane];
        p.h[(size_t)slot * HSTR + tree * HID + lane] = v;
    }
}

// ---------------------------------------------------------------------------
// One level (l = 0..4 for heights 1..5)
// ---------------------------------------------------------------------------
__device__ __forceinline__ void phase_level(const KParams& p, int l, int ggrp, int ngrp, int lane)
{
    const int* meta = p.meta;
    int cnt = meta[MH_CNT + l];
    int pb  = meta[MH_PBASE + l];
    const int* PL  = meta + OFF_PLIST;
    const int* N2S = meta + OFF_N2S;
    const int* CO  = meta + OFF_COFF;

    float wc[HID];
    #pragma unroll
    for (int k = 0; k < HID; ++k) wc[k] = p.node_w[(2 * EMBED + k) * HID + lane];
    float nb = p.node_b[lane];

    int tot = cnt * BATCH;
    for (int i = ggrp; i < tot; i += ngrp) {
        int rr = i >> 8, tree = i & 255;
        int pidx = pb + rr;
        int node = PL[pidx];
        int wslot = N2S[node];
        int e = CO[pidx], e1 = CO[pidx + 1];

        const float* hb = p.h + (size_t)tree * HID + lane;
        float csum = 0.f;
        for (; e + 1 < e1; e += 2) {
            float a0 = hb[(size_t)e * HSTR];
            float a1 = hb[(size_t)(e + 1) * HSTR];
            csum += a0 + a1;
        }
        if (e < e1) csum += hb[(size_t)e * HSTR];

        int gn = tree * N_PER + node;
        int ta = p.tok_a[gn], tb = p.tok_b[gn];
        float v = nb + p.eaw[ta * HID + lane] + p.ebw[tb * HID + lane];
        #pragma unroll
        for (int k = 0; k < HID; ++k) v += __shfl(csum, k, 32) * wc[k];
        v = fmaxf(v, 0.f);
        p.h[(size_t)wslot * HSTR + tree * HID + lane] = v;
    }
}

// ---------------------------------------------------------------------------
// Root child partial sums (16 deterministic chunks per tree)
// ---------------------------------------------------------------------------
__device__ __forceinline__ void phase_rootpart(const KParams& p, int ggrp, int ngrp, int lane)
{
    const int* CO = p.meta + OFF_COFF;
    int P = p.meta[MH_P];
    int e = CO[P - 1], e1 = CO[P];
    int per = (e1 - e + 15) >> 4;
    int tot = BATCH * 16;
    for (int i = ggrp; i < tot; i += ngrp) {
        int tree = i & 255, chunk = i >> 8;
        int s  = e + chunk * per;
        int en = s + per; if (en > e1) en = e1;
        float sum = 0.f;
        for (int c = s; c < en; ++c)
            sum += p.h[(size_t)c * HSTR + tree * HID + lane];
        p.rootpart[((size_t)chunk * BATCH + tree) * HID + lane] = sum;
    }
}

// ---------------------------------------------------------------------------
// Root finish + FF head (tree = group id)
// ---------------------------------------------------------------------------
__device__ __forceinline__ void phase_final(const KParams& p, int tree, int lane)
{
    float csum = 0.f;
    #pragma unroll
    for (int c = 0; c < 16; ++c)
        csum += p.rootpart[((size_t)c * BATCH + tree) * HID + lane];

    int gn = tree * N_PER;   // root = node 0
    int ta = p.tok_a[gn], tb = p.tok_b[gn];
    float v = p.node_b[lane] + p.eaw[ta * HID + lane] + p.ebw[tb * HID + lane];
    #pragma unroll
    for (int k = 0; k < HID; ++k)
        v += __shfl(csum, k, 32) * p.node_w[(2 * EMBED + k) * HID + lane];
    v = fmaxf(v, 0.f);

    float f1 = p.ff_b1[lane];
    #pragma unroll
    for (int k = 0; k < HID; ++k) f1 += __shfl(v, k, 32) * p.ff_w1[k * HID + lane];
    float f2 = p.ff_b2[lane];
    #pragma unroll
    for (int k = 0; k < HID; ++k) f2 += __shfl(f1, k, 32) * p.ff_w2[k * HID + lane];

    float c2 = f2 * p.tail_w[lane];
    #pragma unroll
    for (int off = 16; off > 0; off >>= 1) c2 += __shfl_down(c2, off, 32);
    if (lane == 0) p.out[tree] = c2 + p.tail_b[0];
}

// ---------------------------------------------------------------------------
// Cooperative mono-kernel: all phases, grid.sync between.
// ---------------------------------------------------------------------------
__global__ __launch_bounds__(256, 4) void mono_kernel(KParams p)
{
    cg::grid_group gridg = cg::this_grid();
    const int bid  = blockIdx.x;
    const int tid  = threadIdx.x;
    const int gtid = bid * 256 + tid;
    const int lane = tid & 31;
    const int ggrp = gtid >> 5;

    if (bid == 0) phase_build(p);
    else          phase_prep(p, gtid - 256, (GRID - 1) * 256, lane);
    gridg.sync();

    phase_leafptr(p, ggrp, NGRP, lane);
    gridg.sync();

    for (int l = 0; l < 5; ++l) {
        phase_level(p, l, ggrp, NGRP, lane);
        gridg.sync();
    }

    phase_rootpart(p, ggrp, NGRP, lane);
    gridg.sync();

    if (ggrp < BATCH) phase_final(p, ggrp, lane);
}

// ---------------------------------------------------------------------------
// Fallback standalone kernels (used if cooperative launch is rejected)
// ---------------------------------------------------------------------------
__global__ __launch_bounds__(256) void build_kernel_f(KParams p) { phase_build(p); }

__global__ __launch_bounds__(256) void prep_kernel_f(KParams p) {
    int gtid = blockIdx.x * 256 + threadIdx.x;
    phase_prep(p, gtid, gridDim.x * 256, threadIdx.x & 31);
}
__global__ __launch_bounds__(256) void leafptr_kernel_f(KParams p) {
    int gtid = blockIdx.x * 256 + threadIdx.x;
    phase_leafptr(p, gtid >> 5, (gridDim.x * 256) >> 5, threadIdx.x & 31);
}
__global__ __launch_bounds__(256) void level_kernel_f(KParams p, int l) {
    int gtid = blockIdx.x * 256 + threadIdx.x;
    phase_level(p, l, gtid >> 5, (gridDim.x * 256) >> 5, threadIdx.x & 31);
}
__global__ __launch_bounds__(256) void rootpart_kernel_f(KParams p) {
    int gtid = blockIdx.x * 256 + threadIdx.x;
    phase_rootpart(p, gtid >> 5, (gridDim.x * 256) >> 5, threadIdx.x & 31);
}
__global__ __launch_bounds__(256) void final_kernel_f(KParams p) {
    int gtid = blockIdx.x * 256 + threadIdx.x;
    int tree = gtid >> 5;
    if (tree < BATCH) phase_final(p, tree, threadIdx.x & 31);
}

extern "C" void kernel_launch(void* const* d_in, const int* in_sizes, int n_in,
                              void* d_out, int out_size, void* d_ws, size_t ws_size,
                              hipStream_t stream) {
    char* ws = (char*)d_ws;
    KParams prm;
    prm.kind        = (const int*)d_in[0];
    prm.height      = (const int*)d_in[1];
    prm.parent      = (const int*)d_in[2];
    prm.tok_a       = (const int*)d_in[3];
    prm.tok_b       = (const int*)d_in[4];
    prm.ptr_time    = (const int*)d_in[5];
    prm.first_notes = (const float*)d_in[6];
    prm.lstm_out    = (const float*)d_in[7];
    prm.embedding   = (const float*)d_in[8];
    prm.leaf_w1     = (const float*)d_in[9];
    prm.leaf_b1     = (const float*)d_in[10];
    prm.leaf_w2     = (const float*)d_in[11];
    prm.leaf_b2     = (const float*)d_in[12];
    prm.node_w      = (const float*)d_in[13];
    prm.node_b      = (const float*)d_in[14];
    prm.ptr_w       = (const float*)d_in[15];
    prm.ptr_b       = (const float*)d_in[16];
    prm.ff_w1       = (const float*)d_in[17];
    prm.ff_b1       = (const float*)d_in[18];
    prm.ff_w2       = (const float*)d_in[19];
    prm.ff_b2       = (const float*)d_in[20];
    prm.tail_w      = (const float*)d_in[21];
    prm.tail_b      = (const float*)d_in[22];
    prm.meta     = (int*)ws;
    prm.n2p      = (int*)(ws + N2P_BYTE);
    prm.deg      = (int*)(ws + DEG_BYTE);
    prm.eaw      = (float*)(ws + EAW_BYTE);
    prm.ebw      = (float*)(ws + EBW_BYTE);
    prm.fn_pre   = (float*)(ws + FNPRE_BYTE);
    prm.ptr_pre  = (float*)(ws + PTRPRE_BYTE);
    prm.rootpart = (float*)(ws + ROOTPART_BYTE);
    prm.h        = (float*)(ws + H_BYTE);
    prm.out      = (float*)d_out;

    void* args[] = { &prm };
    hipError_t err = hipLaunchCooperativeKernel((void*)mono_kernel, dim3(GRID),
                                                dim3(256), args, 0, stream);
    if (err != hipSuccess) {
        (void)hipGetLastError();   // clear sticky error; use fallback pipeline
        build_kernel_f<<<1, 256, 0, stream>>>(prm);
        prep_kernel_f<<<512, 256, 0, stream>>>(prm);
        leafptr_kernel_f<<<512, 256, 0, stream>>>(prm);
        for (int l = 0; l < 5; ++l)
            level_kernel_f<<<512, 256, 0, stream>>>(prm, l);
        rootpart_kernel_f<<<512, 256, 0, stream>>>(prm);
        final_kernel_f<<<32, 256, 0, stream>>>(prm);
    }
}

// Round 9
// 492.867 us; speedup vs baseline: 2.3347x; 2.3347x over previous
//
#include <hip/hip_runtime.h>

// Problem constants (fixed by the reference's setup_inputs)
#define BATCH   256
#define N_PER   4096
#define EMBED   16
#define HID     32
#define NOTE    64
#define LSTM_D  64
#define T_LEN   128
#define VOCAB   200
#define HSTR    (BATCH * HID)     // floats per slot (tree-inner layout)

// meta header (ints)
#define MH_C0    0     // kind-0 leaf count (per tree)
#define MH_C1    1     // kind-1 ptr count
#define MH_CNT   2     // [2..6] internal count at level 1..5
#define MH_P     7     // total parents (levels 1..5 + root); root pidx = P-1
#define MH_PBASE 8     // [8..12] pidx base of level 1..5
// meta arrays (ints)
#define OFF_K0N   64
#define OFF_K1N   (OFF_K0N + N_PER)
#define OFF_PLIST (OFF_K1N + N_PER)
#define OFF_N2S   (OFF_PLIST + N_PER)    // node -> h slot (CSR position)
#define OFF_COFF  (OFF_N2S + N_PER)      // N_PER+1 entries, pidx-indexed
// ws byte offsets
#define EAW_BYTE     (1024 * 1024)           // [VOCAB][HID]
#define EBW_BYTE     (EAW_BYTE + 32 * 1024)
#define FNPRE_BYTE   (1536 * 1024)           // [BATCH][HID]
#define PTRPRE_BYTE  (2ull * 1024 * 1024)    // [BATCH*T_LEN][HID] = 4 MB
#define H_BYTE       (8ull * 1024 * 1024)    // [slot][BATCH][HID] = 134 MB

struct KParams {
    const int *kind, *height, *parent, *tok_a, *tok_b, *ptr_time;
    const float *first_notes, *lstm_out, *embedding;
    const float *leaf_w1, *leaf_b1, *leaf_w2, *leaf_b2;
    const float *node_w, *node_b, *ptr_w, *ptr_b;
    const float *ff_w1, *ff_b1, *ff_w2, *ff_b2, *tail_w, *tail_b;
    int *meta;
    float *eaw, *ebw, *fn_pre, *ptr_pre, *h, *out;
};

// ---------------------------------------------------------------------------
// K1: block 0 = structure build (1024 threads, LDS scratch);
//     blocks 1..63 = eaw/ebw tables + fn_pre + ptr_pre (lane=row GEMV).
// ---------------------------------------------------------------------------
__global__ __launch_bounds__(1024) void prep_build_kernel(KParams p)
{
    __shared__ unsigned long long sp64[1024];   //  8 KB
    __shared__ int spint[1024];                 //  4 KB
    __shared__ int sn2p[N_PER];                 // 16 KB
    __shared__ int sdeg[N_PER];                 // 16 KB
    __shared__ int sbases[8], stot[8];

    const int bid = blockIdx.x;
    const int t   = threadIdx.x;
    int* meta = p.meta;

    if (bid == 0) {
        // ---------------- structure build, 4 nodes/thread ----------------
        const int i0 = 4 * t;
        int myb[4];
        unsigned long long clo = 0, chi = 0;
        #pragma unroll
        for (int q = 0; q < 4; ++q) {
            int i = i0 + q;
            int hgt = p.height[i];
            int b;
            if (hgt > 0) { b = 1 + hgt; if (b > 7) b = 7; }  // lvl1..5 -> 2..6, root -> 7
            else b = (p.kind[i] == 0) ? 0 : 1;
            myb[q] = b;
            if (b < 4) clo += 1ull << (16 * b);
            else       chi += 1ull << (16 * (b - 4));
        }
        sp64[t] = clo; __syncthreads();
        for (int off = 1; off < 1024; off <<= 1) {
            unsigned long long v = (t >= off) ? sp64[t - off] : 0ull; __syncthreads();
            sp64[t] += v; __syncthreads();
        }
        unsigned long long ilo = sp64[t];
        if (t == 1023) {
            stot[0] = (int)(ilo & 0xFFFF);         stot[1] = (int)((ilo >> 16) & 0xFFFF);
            stot[2] = (int)((ilo >> 32) & 0xFFFF); stot[3] = (int)((ilo >> 48) & 0xFFFF);
        }
        __syncthreads();
        sp64[t] = chi; __syncthreads();
        for (int off = 1; off < 1024; off <<= 1) {
            unsigned long long v = (t >= off) ? sp64[t - off] : 0ull; __syncthreads();
            sp64[t] += v; __syncthreads();
        }
        unsigned long long ihi = sp64[t];
        if (t == 1023) {
            stot[4] = (int)(ihi & 0xFFFF);         stot[5] = (int)((ihi >> 16) & 0xFFFF);
            stot[6] = (int)((ihi >> 32) & 0xFFFF); stot[7] = (int)((ihi >> 48) & 0xFFFF);
        }
        __syncthreads();
        if (t == 0) {
            int s = 0;
            for (int b = 0; b < 8; ++b) { sbases[b] = s; s += stot[b]; }
            meta[MH_C0] = stot[0];
            meta[MH_C1] = stot[1];
            for (int l = 0; l < 5; ++l) meta[MH_CNT + l]   = stot[2 + l];
            for (int l = 0; l < 5; ++l) meta[MH_PBASE + l] = sbases[2 + l] - sbases[2];
            meta[MH_P] = (sbases[7] - sbases[2]) + stot[7];
        }
        __syncthreads();
        unsigned long long exlo = ilo - clo, exhi = ihi - chi;
        #pragma unroll
        for (int q = 0; q < 4; ++q) {
            int i = i0 + q, b = myb[q];
            int pos;
            if (b < 4) { pos = (int)((exlo >> (16 * b)) & 0xFFFF); exlo += 1ull << (16 * b); }
            else       { pos = (int)((exhi >> (16 * (b - 4))) & 0xFFFF); exhi += 1ull << (16 * (b - 4)); }
            if (b == 0)      meta[OFF_K0N + pos] = i;
            else if (b == 1) meta[OFF_K1N + pos] = i;
            else {
                int pidx = (sbases[b] - sbases[2]) + pos;
                meta[OFF_PLIST + pidx] = i;
                sn2p[i] = pidx;
            }
        }
        #pragma unroll
        for (int q = 0; q < 4; ++q) sdeg[i0 + q] = 0;
        __syncthreads();
        int par[4];
        #pragma unroll
        for (int q = 0; q < 4; ++q) {
            int i = i0 + q; par[q] = p.parent[i];
            if (i != 0) atomicAdd(&sdeg[sn2p[par[q]]], 1);
        }
        __syncthreads();
        int d0 = sdeg[i0], d1 = sdeg[i0 + 1], d2 = sdeg[i0 + 2], d3 = sdeg[i0 + 3];
        int s4 = d0 + d1 + d2 + d3;
        spint[t] = s4; __syncthreads();
        for (int off = 1; off < 1024; off <<= 1) {
            int v = (t >= off) ? spint[t - off] : 0; __syncthreads();
            spint[t] += v; __syncthreads();
        }
        int ex = spint[t] - s4;
        int o0 = ex, o1 = ex + d0, o2 = o1 + d1, o3 = o2 + d2;
        sdeg[i0] = o0; sdeg[i0 + 1] = o1; sdeg[i0 + 2] = o2; sdeg[i0 + 3] = o3;
        meta[OFF_COFF + i0]     = o0;
        meta[OFF_COFF + i0 + 1] = o1;
        meta[OFF_COFF + i0 + 2] = o2;
        meta[OFF_COFF + i0 + 3] = o3;
        if (t == 1023) meta[OFF_COFF + N_PER] = o3 + d3;
        __syncthreads();
        #pragma unroll
        for (int q = 0; q < 4; ++q) {
            int i = i0 + q;
            if (i != 0) {
                int slot = atomicAdd(&sdeg[sn2p[par[q]]], 1);
                meta[OFF_N2S + i] = slot;
            }
        }
    } else {
        // ---------------- prep on blocks 1..63 ----------------
        int wt = (bid - 1) * 1024 + t;
        const int nw = 63 * 1024;
        int lane = t & 31;

        // eaw/ebw tables
        for (int idx = wt; idx < VOCAB * HID; idx += nw) {
            int v = idx >> 5, d = idx & 31;
            float sa = 0.f, sb = 0.f;
            #pragma unroll
            for (int k = 0; k < EMBED; ++k) {
                float e = p.embedding[v * EMBED + k];
                sa += e * p.node_w[k * HID + d];
                sb += e * p.node_w[(EMBED + k) * HID + d];
            }
            p.eaw[idx] = sa;
            p.ebw[idx] = sb;
        }
        // fn_pre (256 rows, group-of-32)
        {
            int wg = wt >> 5, nwg = nw >> 5;
            for (int r = wg; r < BATCH; r += nwg) {
                const float* fn = p.first_notes + (size_t)r * NOTE;
                float v = p.ptr_b[lane];
                #pragma unroll
                for (int k = 0; k < NOTE; ++k) v += fn[k] * p.ptr_w[k * HID + lane];
                p.fn_pre[r * HID + lane] = v;
            }
        }
        // ptr_pre GEMV, lane=row: wave64 handles 64 consecutive rows
        {
            int wave = wt >> 6, nwave = nw >> 6;
            int lane64 = wt & 63;
            for (int wb = wave; wb < (BATCH * T_LEN) / 64; wb += nwave) {
                int row = wb * 64 + lane64;
                const float4* lo4 = (const float4*)(p.lstm_out + (size_t)row * LSTM_D);
                float4 v0 = {0,0,0,0}, v1 = v0, v2 = v0, v3 = v0,
                       v4 = v0, v5 = v0, v6 = v0, v7 = v0;
                #pragma unroll
                for (int qq = 0; qq < 16; ++qq) {
                    float4 a = lo4[qq];
                    #define PMV(CK, KIDX) { \
                        const float4* wr = (const float4*)(p.ptr_w + (NOTE + (KIDX)) * HID); \
                        float4 w; \
                        w = wr[0]; v0.x += (CK)*w.x; v0.y += (CK)*w.y; v0.z += (CK)*w.z; v0.w += (CK)*w.w; \
                        w = wr[1]; v1.x += (CK)*w.x; v1.y += (CK)*w.y; v1.z += (CK)*w.z; v1.w += (CK)*w.w; \
                        w = wr[2]; v2.x += (CK)*w.x; v2.y += (CK)*w.y; v2.z += (CK)*w.z; v2.w += (CK)*w.w; \
                        w = wr[3]; v3.x += (CK)*w.x; v3.y += (CK)*w.y; v3.z += (CK)*w.z; v3.w += (CK)*w.w; \
                        w = wr[4]; v4.x += (CK)*w.x; v4.y += (CK)*w.y; v4.z += (CK)*w.z; v4.w += (CK)*w.w; \
                        w = wr[5]; v5.x += (CK)*w.x; v5.y += (CK)*w.y; v5.z += (CK)*w.z; v5.w += (CK)*w.w; \
                        w = wr[6]; v6.x += (CK)*w.x; v6.y += (CK)*w.y; v6.z += (CK)*w.z; v6.w += (CK)*w.w; \
                        w = wr[7]; v7.x += (CK)*w.x; v7.y += (CK)*w.y; v7.z += (CK)*w.z; v7.w += (CK)*w.w; }
                    PMV(a.x, 4 * qq + 0)
                    PMV(a.y, 4 * qq + 1)
                    PMV(a.z, 4 * qq + 2)
                    PMV(a.w, 4 * qq + 3)
                }
                float4* o = (float4*)(p.ptr_pre + (size_t)row * HID);
                o[0] = v0; o[1] = v1; o[2] = v2; o[3] = v3;
                o[4] = v4; o[5] = v5; o[6] = v6; o[7] = v7;
            }
        }
    }
}

// ---------------------------------------------------------------------------
// K2: leaves + ptr rows -> h (group-of-32, verified numerics from R6)
// ---------------------------------------------------------------------------
__global__ __launch_bounds__(256, 4) void leafptr_kernel(KParams p)
{
    const int* meta = p.meta;
    const int* N2S  = meta + OFF_N2S;
    int lane = threadIdx.x & 31;
    int ggrp = (blockIdx.x * 256 + threadIdx.x) >> 5;
    int ngrp = (gridDim.x * 256) >> 5;

    int c0 = meta[MH_C0];
    const int* K0N = meta + OFF_K0N;
    float w1a[EMBED], w1b[EMBED], w2c[HID];
    #pragma unroll
    for (int k = 0; k < EMBED; ++k) {
        w1a[k] = p.leaf_w1[k * HID + lane];
        w1b[k] = p.leaf_w1[(EMBED + k) * HID + lane];
    }
    #pragma unroll
    for (int k = 0; k < HID; ++k) w2c[k] = p.leaf_w2[k * HID + lane];
    float b1 = p.leaf_b1[lane], b2 = p.leaf_b2[lane];

    int tot = c0 * BATCH;
    for (int i = ggrp; i < tot; i += ngrp) {
        int j = i >> 8, tree = i & 255;
        int node = K0N[j], slot = N2S[node];
        int gn = tree * N_PER + node;
        const float* ea = p.embedding + p.tok_a[gn] * EMBED;
        const float* eb = p.embedding + p.tok_b[gn] * EMBED;
        float hid = b1;
        #pragma unroll
        for (int k = 0; k < EMBED; ++k) hid += ea[k] * w1a[k];
        #pragma unroll
        for (int k = 0; k < EMBED; ++k) hid += eb[k] * w1b[k];
        float v = b2;
        #pragma unroll
        for (int k = 0; k < HID; ++k) v += __shfl(hid, k, 32) * w2c[k];
        p.h[(size_t)slot * HSTR + tree * HID + lane] = v;
    }

    int c1 = meta[MH_C1];
    const int* K1N = meta + OFF_K1N;
    int tot1 = c1 * BATCH;
    for (int i = ggrp; i < tot1; i += ngrp) {
        int j = i >> 8, tree = i & 255;
        int node = K1N[j], slot = N2S[node];
        int tt = p.ptr_time[tree * N_PER + node];
        float v = p.fn_pre[tree * HID + lane]
                + p.ptr_pre[((size_t)tree * T_LEN + tt) * HID + lane];
        p.h[(size_t)slot * HSTR + tree * HID + lane] = v;
    }
}

// ---------------------------------------------------------------------------
// K3..K7: level pass, lane=tree. wave64 = one parent x 64 trees.
// csum in registers, matvec = pure FMA with wave-uniform W (no shuffles).
// ---------------------------------------------------------------------------
__global__ __launch_bounds__(256, 4) void level_kernel(KParams p, int l)
{
    const int* meta = p.meta;
    int cnt = meta[MH_CNT + l];
    int pb  = meta[MH_PBASE + l];
    const int* PL  = meta + OFF_PLIST;
    const int* N2S = meta + OFF_N2S;
    const int* CO  = meta + OFF_COFF;
    const float* W = p.node_w + 2 * EMBED * HID;   // [32][32]

    int wave   = (blockIdx.x * 256 + threadIdx.x) >> 6;
    int nwave  = (gridDim.x * 256) >> 6;
    int lane64 = threadIdx.x & 63;

    int tot = cnt * 4;   // parent x 4 tree-chunks of 64
    for (int i = wave; i < tot; i += nwave) {
        int rr = i >> 2, chunk = i & 3;
        int tree = chunk * 64 + lane64;
        int pidx = pb + rr;
        int node = PL[pidx], wslot = N2S[node];
        int e = CO[pidx], e1 = CO[pidx + 1];

        float4 c0 = {0,0,0,0}, c1 = c0, c2 = c0, c3 = c0,
               c4 = c0, c5 = c0, c6 = c0, c7 = c0;
        for (int c = e; c < e1; ++c) {
            const float4* row = (const float4*)(p.h + (size_t)c * HSTR + tree * HID);
            float4 x;
            x = row[0]; c0.x += x.x; c0.y += x.y; c0.z += x.z; c0.w += x.w;
            x = row[1]; c1.x += x.x; c1.y += x.y; c1.z += x.z; c1.w += x.w;
            x = row[2]; c2.x += x.x; c2.y += x.y; c2.z += x.z; c2.w += x.w;
            x = row[3]; c3.x += x.x; c3.y += x.y; c3.z += x.z; c3.w += x.w;
            x = row[4]; c4.x += x.x; c4.y += x.y; c4.z += x.z; c4.w += x.w;
            x = row[5]; c5.x += x.x; c5.y += x.y; c5.z += x.z; c5.w += x.w;
            x = row[6]; c6.x += x.x; c6.y += x.y; c6.z += x.z; c6.w += x.w;
            x = row[7]; c7.x += x.x; c7.y += x.y; c7.z += x.z; c7.w += x.w;
        }

        int gn = tree * N_PER + node;
        int ta = p.tok_a[gn], tb = p.tok_b[gn];
        const float4* A = (const float4*)(p.eaw + ta * HID);
        const float4* B = (const float4*)(p.ebw + tb * HID);
        const float4* NB = (const float4*)p.node_b;
        float4 v0, v1, v2, v3, v4, v5, v6, v7;
        #define INITV(VQ, Q) { float4 nb = NB[Q], a = A[Q], b = B[Q]; \
            VQ.x = nb.x + a.x + b.x; VQ.y = nb.y + a.y + b.y; \
            VQ.z = nb.z + a.z + b.z; VQ.w = nb.w + a.w + b.w; }
        INITV(v0,0) INITV(v1,1) INITV(v2,2) INITV(v3,3)
        INITV(v4,4) INITV(v5,5) INITV(v6,6) INITV(v7,7)

        #define MV(CK, KIDX) { \
            const float4* wr = (const float4*)(W + (KIDX) * HID); float4 w; \
            w = wr[0]; v0.x += (CK)*w.x; v0.y += (CK)*w.y; v0.z += (CK)*w.z; v0.w += (CK)*w.w; \
            w = wr[1]; v1.x += (CK)*w.x; v1.y += (CK)*w.y; v1.z += (CK)*w.z; v1.w += (CK)*w.w; \
            w = wr[2]; v2.x += (CK)*w.x; v2.y += (CK)*w.y; v2.z += (CK)*w.z; v2.w += (CK)*w.w; \
            w = wr[3]; v3.x += (CK)*w.x; v3.y += (CK)*w.y; v3.z += (CK)*w.z; v3.w += (CK)*w.w; \
            w = wr[4]; v4.x += (CK)*w.x; v4.y += (CK)*w.y; v4.z += (CK)*w.z; v4.w += (CK)*w.w; \
            w = wr[5]; v5.x += (CK)*w.x; v5.y += (CK)*w.y; v5.z += (CK)*w.z; v5.w += (CK)*w.w; \
            w = wr[6]; v6.x += (CK)*w.x; v6.y += (CK)*w.y; v6.z += (CK)*w.z; v6.w += (CK)*w.w; \
            w = wr[7]; v7.x += (CK)*w.x; v7.y += (CK)*w.y; v7.z += (CK)*w.z; v7.w += (CK)*w.w; }
        MV(c0.x, 0)  MV(c0.y, 1)  MV(c0.z, 2)  MV(c0.w, 3)
        MV(c1.x, 4)  MV(c1.y, 5)  MV(c1.z, 6)  MV(c1.w, 7)
        MV(c2.x, 8)  MV(c2.y, 9)  MV(c2.z, 10) MV(c2.w, 11)
        MV(c3.x, 12) MV(c3.y, 13) MV(c3.z, 14) MV(c3.w, 15)
        MV(c4.x, 16) MV(c4.y, 17) MV(c4.z, 18) MV(c4.w, 19)
        MV(c5.x, 20) MV(c5.y, 21) MV(c5.z, 22) MV(c5.w, 23)
        MV(c6.x, 24) MV(c6.y, 25) MV(c6.z, 26) MV(c6.w, 27)
        MV(c7.x, 28) MV(c7.y, 29) MV(c7.z, 30) MV(c7.w, 31)

        float4* o = (float4*)(p.h + (size_t)wslot * HSTR + tree * HID);
        #define STR(VQ, Q) { VQ.x = fmaxf(VQ.x, 0.f); VQ.y = fmaxf(VQ.y, 0.f); \
            VQ.z = fmaxf(VQ.z, 0.f); VQ.w = fmaxf(VQ.w, 0.f); o[Q] = VQ; }
        STR(v0,0) STR(v1,1) STR(v2,2) STR(v3,3)
        STR(v4,4) STR(v5,5) STR(v6,6) STR(v7,7)
    }
}

// ---------------------------------------------------------------------------
// K8: one block per tree: gather root children (contiguous slots), LDS
// reduce, finish root h, FF head -> out[tree].
// ---------------------------------------------------------------------------
__global__ __launch_bounds__(256, 4) void root_final_kernel(KParams p)
{
    __shared__ float red[8][HID];
    const int* meta = p.meta;
    const int* CO = meta + OFF_COFF;
    int P = meta[MH_P];
    int e = CO[P - 1], e1 = CO[P];

    int tree = blockIdx.x;
    int grp  = threadIdx.x >> 5;
    int lane = threadIdx.x & 31;

    float part = 0.f;
    for (int c = e + grp; c < e1; c += 8)
        part += p.h[(size_t)c * HSTR + tree * HID + lane];
    red[grp][lane] = part;
    __syncthreads();

    if (grp == 0) {
        float csum = red[0][lane];
        #pragma unroll
        for (int g = 1; g < 8; ++g) csum += red[g][lane];

        int gn = tree * N_PER;   // root = node 0
        int ta = p.tok_a[gn], tb = p.tok_b[gn];
        float v = p.node_b[lane] + p.eaw[ta * HID + lane] + p.ebw[tb * HID + lane];
        #pragma unroll
        for (int k = 0; k < HID; ++k)
            v += __shfl(csum, k, 32) * p.node_w[(2 * EMBED + k) * HID + lane];
        v = fmaxf(v, 0.f);

        float f1 = p.ff_b1[lane];
        #pragma unroll
        for (int k = 0; k < HID; ++k) f1 += __shfl(v, k, 32) * p.ff_w1[k * HID + lane];
        float f2 = p.ff_b2[lane];
        #pragma unroll
        for (int k = 0; k < HID; ++k) f2 += __shfl(f1, k, 32) * p.ff_w2[k * HID + lane];

        float c2 = f2 * p.tail_w[lane];
        #pragma unroll
        for (int off = 16; off > 0; off >>= 1) c2 += __shfl_down(c2, off, 32);
        if (lane == 0) p.out[tree] = c2 + p.tail_b[0];
    }
}

extern "C" void kernel_launch(void* const* d_in, const int* in_sizes, int n_in,
                              void* d_out, int out_size, void* d_ws, size_t ws_size,
                              hipStream_t stream) {
    char* ws = (char*)d_ws;
    KParams prm;
    prm.kind        = (const int*)d_in[0];
    prm.height      = (const int*)d_in[1];
    prm.parent      = (const int*)d_in[2];
    prm.tok_a       = (const int*)d_in[3];
    prm.tok_b       = (const int*)d_in[4];
    prm.ptr_time    = (const int*)d_in[5];
    prm.first_notes = (const float*)d_in[6];
    prm.lstm_out    = (const float*)d_in[7];
    prm.embedding   = (const float*)d_in[8];
    prm.leaf_w1     = (const float*)d_in[9];
    prm.leaf_b1     = (const float*)d_in[10];
    prm.leaf_w2     = (const float*)d_in[11];
    prm.leaf_b2     = (const float*)d_in[12];
    prm.node_w      = (const float*)d_in[13];
    prm.node_b      = (const float*)d_in[14];
    prm.ptr_w       = (const float*)d_in[15];
    prm.ptr_b       = (const float*)d_in[16];
    prm.ff_w1       = (const float*)d_in[17];
    prm.ff_b1       = (const float*)d_in[18];
    prm.ff_w2       = (const float*)d_in[19];
    prm.ff_b2       = (const float*)d_in[20];
    prm.tail_w      = (const float*)d_in[21];
    prm.tail_b      = (const float*)d_in[22];
    prm.meta     = (int*)ws;
    prm.eaw      = (float*)(ws + EAW_BYTE);
    prm.ebw      = (float*)(ws + EBW_BYTE);
    prm.fn_pre   = (float*)(ws + FNPRE_BYTE);
    prm.ptr_pre  = (float*)(ws + PTRPRE_BYTE);
    prm.h        = (float*)(ws + H_BYTE);
    prm.out      = (float*)d_out;

    prep_build_kernel<<<64, 1024, 0, stream>>>(prm);
    leafptr_kernel<<<1024, 256, 0, stream>>>(prm);
    for (int l = 0; l < 5; ++l)
        level_kernel<<<2048, 256, 0, stream>>>(prm, l);
    root_final_kernel<<<BATCH, 256, 0, stream>>>(prm);
}